// Round 1
// baseline (1569.180 us; speedup 1.0000x reference)
//
#include <hip/hip_runtime.h>

// ---- problem constants ----
#define CIN   16
#define COUTC 8
#define HIN   8
#define WINW  8
#define KK    3
#define SST   2
#define PPD   1
#define HOUTC 16
#define WOUTC 16
#define OHI   4
#define OWI   4
#define OHO   8
#define OWO   8
#define IN_F  2304   // CIN*K*K*OHI*OWI
#define OUT_F 4608   // COUT*K*K*OHO*OWO
#define BATCH 64
#define NSPL  8      // GRID_SIZE + SPLINE_ORDER

// uniform knot grid: g[t] = (t-3)*0.4 - 1, t = 0..11
__device__ __forceinline__ float gridv(int t) {
    return (float)(t - 3) * 0.4f - 1.0f;
}

// ---------------------------------------------------------------
// prep: u = unfold(x); Ab[f*64+b] = silu(u); Aspl[(f*64+b)*8+j] = bases_j(u)
// ---------------------------------------------------------------
__global__ __launch_bounds__(256) void prep_kernel(const float* __restrict__ x,
                                                   float* __restrict__ Ab,
                                                   float* __restrict__ Aspl) {
    int tid = blockIdx.x * 256 + threadIdx.x;   // tid = f*64 + b
    if (tid >= IN_F * BATCH) return;
    int f = tid >> 6, b = tid & 63;
    int ckk = f >> 4, s = f & 15;               // f = ckk*16 + s
    int c = ckk / 9, r = ckk % 9;
    int ki = r / 3, kj = r % 3;
    int oh = s >> 2, ow = s & 3;
    int h = ki + oh * SST - PPD;
    int w = kj + ow * SST - PPD;
    float u = 0.0f;
    if (h >= 0 && h < HIN && w >= 0 && w < WINW)
        u = x[((b * CIN + c) * HIN + h) * WINW + w];

    // silu
    Ab[tid] = u / (1.0f + __expf(-u));

    // degree-3 B-spline bases, Cox-de Boor (matches reference recurrence)
    float bs[11];
#pragma unroll
    for (int t = 0; t < 11; ++t)
        bs[t] = (u >= gridv(t) && u < gridv(t + 1)) ? 1.0f : 0.0f;
#pragma unroll
    for (int k = 1; k <= 3; ++k) {
#pragma unroll
        for (int i = 0; i < 11 - 3; ++i) {      // only first 11-k entries matter; 8 covers final need
            // guard: for k<3 we need up to index 11-k-1; compute full range
        }
#pragma unroll
        for (int i = 0; i < 11; ++i) {
            if (i < 11 - k) {
                float g_i  = gridv(i);
                float g_ik = gridv(i + k);
                float g_i1 = gridv(i + 1);
                float g_k1 = gridv(i + k + 1);
                bs[i] = (u - g_i) / (g_ik - g_i) * bs[i]
                      + (g_k1 - u) / (g_k1 - g_i1) * bs[i + 1];
            }
        }
    }
    float* dst = &Aspl[(size_t)tid * NSPL];
#pragma unroll
    for (int j = 0; j < NSPL; ++j) dst[j] = bs[j];
}

// ---------------------------------------------------------------
// gemm + fused fold
// lane = batch (64); each wave owns NO_WAVE output features; K-split over f
// ---------------------------------------------------------------
#define NO_BLOCK 32
#define NO_WAVE  8
#define KSPLIT   8
#define FCHUNK   (IN_F / KSPLIT)   // 288

__global__ __launch_bounds__(256) void gemm_fold_kernel(
    const float* __restrict__ Wb,    // (OUT_F, IN_F)
    const float* __restrict__ Ws,    // (OUT_F, IN_F, 8)
    const float* __restrict__ Sc,    // (OUT_F, IN_F)
    const float* __restrict__ Ab,    // (IN_F, 64)
    const float* __restrict__ Aspl,  // (IN_F, 64, 8)
    float* __restrict__ out)         // (64, 8, 16, 16)
{
    int lane = threadIdx.x & 63;                                   // batch
    int wave = __builtin_amdgcn_readfirstlane(threadIdx.x >> 6);   // force SGPR
    int otile = blockIdx.x / KSPLIT;
    int ks    = blockIdx.x % KSPLIT;
    int f0    = ks * FCHUNK;
    int o0    = otile * NO_BLOCK + wave * NO_WAVE;

    float acc[NO_WAVE];
#pragma unroll
    for (int i = 0; i < NO_WAVE; ++i) acc[i] = 0.0f;

    for (int f = f0; f < f0 + FCHUNK; ++f) {
        float a = Ab[f * 64 + lane];
        const float4* ap = (const float4*)&Aspl[(size_t)(f * 64 + lane) * NSPL];
        float4 a0 = ap[0];
        float4 a1 = ap[1];
#pragma unroll
        for (int i = 0; i < NO_WAVE; ++i) {
            int o = o0 + i;
            float wb = Wb[o * IN_F + f];                       // wave-uniform -> s_load
            const float* wsp = &Ws[((size_t)o * IN_F + f) * NSPL];
            float t = wsp[0] * a0.x + wsp[1] * a0.y + wsp[2] * a0.z + wsp[3] * a0.w
                    + wsp[4] * a1.x + wsp[5] * a1.y + wsp[6] * a1.z + wsp[7] * a1.w;
            acc[i] += wb * a + Sc[o * IN_F + f] * t;
        }
    }

    // fused fold: feature o -> (c, h, w) output pixel (or dropped at border)
#pragma unroll
    for (int i = 0; i < NO_WAVE; ++i) {
        int o = o0 + i;
        int m = o >> 6, pos = o & 63;           // o = m*64 + pos
        int c = m / 9, r = m % 9;
        int ki = r / 3, kj = r % 3;
        int oh = pos >> 3, ow = pos & 7;
        int h = ki + oh * SST - PPD;
        int w = kj + ow * SST - PPD;
        if (h >= 0 && h < HOUTC && w >= 0 && w < WOUTC)
            atomicAdd(&out[((lane * COUTC + c) * HOUTC + h) * WOUTC + w], acc[i]);
    }
}

extern "C" void kernel_launch(void* const* d_in, const int* in_sizes, int n_in,
                              void* d_out, int out_size, void* d_ws, size_t ws_size,
                              hipStream_t stream) {
    const float* x  = (const float*)d_in[0];
    const float* Wb = (const float*)d_in[1];
    const float* Ws = (const float*)d_in[2];
    const float* Sc = (const float*)d_in[3];
    // d_in[4] = grid, recomputed analytically in-kernel (uniform knots)

    float* out  = (float*)d_out;
    float* Ab   = (float*)d_ws;                  // IN_F*64 floats
    float* Aspl = Ab + (size_t)IN_F * BATCH;     // IN_F*64*8 floats

    hipMemsetAsync(d_out, 0, (size_t)out_size * sizeof(float), stream);

    prep_kernel<<<(IN_F * BATCH + 255) / 256, 256, 0, stream>>>(x, Ab, Aspl);

    gemm_fold_kernel<<<(OUT_F / NO_BLOCK) * KSPLIT, 256, 0, stream>>>(
        Wb, Ws, Sc, Ab, Aspl, out);
}

// Round 2
// 320.838 us; speedup vs baseline: 4.8909x; 4.8909x over previous
//
#include <hip/hip_runtime.h>

// ---- problem constants ----
#define CIN   16
#define COUTC 8
#define HIN   8
#define WINW  8
#define SST   2
#define PPD   1
#define HOUTC 16
#define WOUTC 16
#define IN_F  2304   // CIN*3*3*4*4
#define OUT_F 4608   // COUT*3*3*8*8
#define BATCH 64
#define NSPL  8      // GRID_SIZE + SPLINE_ORDER

// ---- gemm tiling ----
#define KSPLIT   16
#define FCHUNK   (IN_F / KSPLIT)   // 144
#define FT       8                 // f's staged per LDS tile
#define NTILES   (FCHUNK / FT)     // 18
#define WS_STRIDE 68               // padded o-stride for Ws_lds rows (16B-aligned, bank-friendly)

// uniform knot grid: g[t] = (t-3)*0.4 - 1, t = 0..11
__device__ __forceinline__ float gridv(int t) {
    return (float)(t - 3) * 0.4f - 1.0f;
}

// async global->LDS, 16B per lane; dest = wave-uniform base + lane*16
__device__ __forceinline__ void gload_lds16(const float* g, float* l) {
    __builtin_amdgcn_global_load_lds(
        (const __attribute__((address_space(1))) unsigned int*)g,
        (__attribute__((address_space(3))) unsigned int*)l, 16, 0, 0);
}

// ---------------------------------------------------------------
// prep: u = unfold(x); Ab[f*64+b] = silu(u); Bs[(f*8+t)*64+b] = bases_t(u)
// ---------------------------------------------------------------
__global__ __launch_bounds__(256) void prep_kernel(const float* __restrict__ x,
                                                   float* __restrict__ Ab,
                                                   float* __restrict__ Bs) {
    int tid = blockIdx.x * 256 + threadIdx.x;   // tid = f*64 + b
    if (tid >= IN_F * BATCH) return;
    int f = tid >> 6, b = tid & 63;
    int ckk = f >> 4, s = f & 15;               // f = ckk*16 + s
    int c = ckk / 9, r = ckk % 9;
    int ki = r / 3, kj = r % 3;
    int oh = s >> 2, ow = s & 3;
    int h = ki + oh * SST - PPD;
    int w = kj + ow * SST - PPD;
    float u = 0.0f;
    if (h >= 0 && h < HIN && w >= 0 && w < WINW)
        u = x[((b * CIN + c) * HIN + h) * WINW + w];

    Ab[tid] = u / (1.0f + __expf(-u));

    // degree-3 B-spline bases (Cox-de Boor, matches reference recurrence)
    float bs[11];
#pragma unroll
    for (int t = 0; t < 11; ++t)
        bs[t] = (u >= gridv(t) && u < gridv(t + 1)) ? 1.0f : 0.0f;
#pragma unroll
    for (int k = 1; k <= 3; ++k) {
#pragma unroll
        for (int i = 0; i < 11; ++i) {
            if (i < 11 - k) {
                float g_i  = gridv(i);
                float g_ik = gridv(i + k);
                float g_i1 = gridv(i + 1);
                float g_k1 = gridv(i + k + 1);
                bs[i] = (u - g_i) / (g_ik - g_i) * bs[i]
                      + (g_k1 - u) / (g_k1 - g_i1) * bs[i + 1];
            }
        }
    }
#pragma unroll
    for (int t = 0; t < NSPL; ++t)
        Bs[(f * NSPL + t) * 64 + b] = bs[t];
}

// ---------------------------------------------------------------
// gemm + fused fold, LDS-tiled.
// Block: 256 threads = 16 o-groups x 16 b-groups; thread tile 4o x 4b.
// Block covers 64 outputs x 64 batches; K-split over f.
// ---------------------------------------------------------------
__global__ __launch_bounds__(256, 4) void gemm_fold_kernel(
    const float* __restrict__ Wb,    // (OUT_F, IN_F)
    const float* __restrict__ Ws,    // (OUT_F, IN_F, 8)
    const float* __restrict__ Sc,    // (OUT_F, IN_F)
    const float* __restrict__ Ab,    // (IN_F, 64)   silu
    const float* __restrict__ Bs,    // (IN_F, 8, 64) spline bases
    float* __restrict__ out)         // (64, 8, 16, 16)
{
    __shared__ float Bs_lds[FT * 8 * 64];        // [f][t][b]   4096 floats (linear: gload_lds)
    __shared__ float Ab_lds[FT * 64];            // [f][b]       512 floats (linear: gload_lds)
    __shared__ float Ws_lds[FT * 8 * WS_STRIDE]; // [f][t][o+pad] 4352 floats (Sc pre-folded)
    __shared__ float Wb_lds[FT * 64];            // [f][o]       512 floats

    const int tid  = threadIdx.x;
    const int lane = tid & 63;
    const int wave = tid >> 6;
    const int o4 = (tid & 15) * 4;   // this thread's 4 outputs within the 64-o tile
    const int b4 = (tid >> 4) * 4;   // this thread's 4 batches

    const int ot = blockIdx.x / KSPLIT;
    const int ks = blockIdx.x % KSPLIT;
    const int o0 = ot * 64;
    const int fstart = ks * FCHUNK;

    // staging role: thread covers (o_s, fi_s..fi_s+1)
    const int o_s  = tid >> 2;            // 0..63
    const int fi_s = (tid & 3) * 2;       // 0,2,4,6

    float acc[4][4];
#pragma unroll
    for (int i = 0; i < 4; ++i)
#pragma unroll
        for (int j = 0; j < 4; ++j) acc[i][j] = 0.0f;

    for (int tile = 0; tile < NTILES; ++tile) {
        const int f0g = fstart + tile * FT;

        __syncthreads();   // previous tile fully consumed before overwrite

        // --- stage activations via global_load_lds (linear layouts) ---
        {
            const float* src = Bs + (size_t)f0g * 512;   // FT*8*64 = 4096 floats
#pragma unroll
            for (int r = 0; r < 4; ++r) {
                int chunk = r * 1024 + wave * 256;       // floats
                gload_lds16(src + chunk + lane * 4, &Bs_lds[chunk]);
            }
            if (wave < 2) {
                int chunk = wave * 256;
                gload_lds16(Ab + (size_t)f0g * 64 + chunk + lane * 4, &Ab_lds[chunk]);
            }
        }

        // --- stage weights (transpose to [f][t][o], fold Sc) ---
        {
            size_t wrow = (size_t)(o0 + o_s) * IN_F + f0g + fi_s;
            float2 wb2 = *(const float2*)&Wb[wrow];
            float2 sc2 = *(const float2*)&Sc[wrow];
            float4 a0 = *(const float4*)&Ws[wrow * 8];
            float4 a1 = *(const float4*)&Ws[wrow * 8 + 4];
            float4 b0 = *(const float4*)&Ws[wrow * 8 + 8];
            float4 b1 = *(const float4*)&Ws[wrow * 8 + 12];

            Wb_lds[fi_s * 64 + o_s]       = wb2.x;
            Wb_lds[(fi_s + 1) * 64 + o_s] = wb2.y;

            float* wdst = &Ws_lds[fi_s * 8 * WS_STRIDE + o_s];
            wdst[0 * WS_STRIDE] = a0.x * sc2.x;
            wdst[1 * WS_STRIDE] = a0.y * sc2.x;
            wdst[2 * WS_STRIDE] = a0.z * sc2.x;
            wdst[3 * WS_STRIDE] = a0.w * sc2.x;
            wdst[4 * WS_STRIDE] = a1.x * sc2.x;
            wdst[5 * WS_STRIDE] = a1.y * sc2.x;
            wdst[6 * WS_STRIDE] = a1.z * sc2.x;
            wdst[7 * WS_STRIDE] = a1.w * sc2.x;
            float* wdst2 = wdst + 8 * WS_STRIDE;
            wdst2[0 * WS_STRIDE] = b0.x * sc2.y;
            wdst2[1 * WS_STRIDE] = b0.y * sc2.y;
            wdst2[2 * WS_STRIDE] = b0.z * sc2.y;
            wdst2[3 * WS_STRIDE] = b0.w * sc2.y;
            wdst2[4 * WS_STRIDE] = b1.x * sc2.y;
            wdst2[5 * WS_STRIDE] = b1.y * sc2.y;
            wdst2[6 * WS_STRIDE] = b1.z * sc2.y;
            wdst2[7 * WS_STRIDE] = b1.w * sc2.y;
        }

        __syncthreads();   // waits vmcnt(0) + lgkmcnt(0): staging complete

        // --- compute: 8 f's, thread tile 4o x 4b, all float4 LDS reads ---
#pragma unroll
        for (int f = 0; f < FT; ++f) {
            float4 a  = *(const float4*)&Ab_lds[f * 64 + b4];
            float4 wb = *(const float4*)&Wb_lds[f * 64 + o4];
            const float wbv[4] = {wb.x, wb.y, wb.z, wb.w};
            const float av[4]  = {a.x, a.y, a.z, a.w};
#pragma unroll
            for (int i = 0; i < 4; ++i)
#pragma unroll
                for (int j = 0; j < 4; ++j)
                    acc[i][j] += wbv[i] * av[j];
#pragma unroll
            for (int t = 0; t < 8; ++t) {
                float4 bsv = *(const float4*)&Bs_lds[(f * 8 + t) * 64 + b4];
                float4 wsv = *(const float4*)&Ws_lds[(f * 8 + t) * WS_STRIDE + o4];
                const float wv[4] = {wsv.x, wsv.y, wsv.z, wsv.w};
                const float bv[4] = {bsv.x, bsv.y, bsv.z, bsv.w};
#pragma unroll
                for (int i = 0; i < 4; ++i)
#pragma unroll
                    for (int j = 0; j < 4; ++j)
                        acc[i][j] += wv[i] * bv[j];
            }
        }
    }

    // --- fused fold: output feature -> (c,h,w), atomic accumulate ---
#pragma unroll
    for (int i = 0; i < 4; ++i) {
        int o = o0 + o4 + i;
        int m = o >> 6, pos = o & 63;
        int c = m / 9, r = m % 9;
        int ki = r / 3, kj = r % 3;
        int oh = pos >> 3, ow = pos & 7;
        int h = ki + oh * SST - PPD;
        int w = kj + ow * SST - PPD;
        if (h >= 0 && h < HOUTC && w >= 0 && w < WOUTC) {
#pragma unroll
            for (int j = 0; j < 4; ++j) {
                int b = b4 + j;
                atomicAdd(&out[((b * COUTC + c) * HOUTC + h) * WOUTC + w], acc[i][j]);
            }
        }
    }
}

extern "C" void kernel_launch(void* const* d_in, const int* in_sizes, int n_in,
                              void* d_out, int out_size, void* d_ws, size_t ws_size,
                              hipStream_t stream) {
    const float* x  = (const float*)d_in[0];
    const float* Wb = (const float*)d_in[1];
    const float* Ws = (const float*)d_in[2];
    const float* Sc = (const float*)d_in[3];
    // d_in[4] = grid, recomputed analytically in-kernel (uniform knots)

    float* out = (float*)d_out;
    float* Ab  = (float*)d_ws;                   // IN_F*64 floats
    float* Bs  = Ab + (size_t)IN_F * BATCH;      // IN_F*8*64 floats

    hipMemsetAsync(d_out, 0, (size_t)out_size * sizeof(float), stream);

    prep_kernel<<<(IN_F * BATCH + 255) / 256, 256, 0, stream>>>(x, Ab, Bs);

    gemm_fold_kernel<<<(OUT_F / 64) * KSPLIT, 256, 0, stream>>>(
        Wb, Ws, Sc, Ab, Bs, out);
}

// Round 3
// 144.461 us; speedup vs baseline: 10.8623x; 2.2209x over previous
//
#include <hip/hip_runtime.h>

// ---- problem constants ----
#define CIN   16
#define COUTC 8
#define HIN   8
#define WINW  8
#define SST   2
#define PPD   1
#define HOUTC 16
#define WOUTC 16
#define IN_F  2304   // CIN*3*3*4*4
#define OUT_F 4608   // COUT*3*3*8*8
#define BATCH 64

// ---- gemm decomposition ----
#define OS 6          // outer K-splits (partial buffers)
#define FW 96         // f's per wave: IN_F / (OS*4 waves)

typedef __bf16 bf16x8 __attribute__((ext_vector_type(8)));
typedef float  f32x4  __attribute__((ext_vector_type(4)));

// uniform knot grid: g[t] = (t-3)*0.4 - 1
__device__ __forceinline__ float gridv(int t) {
    return (float)(t - 3) * 0.4f - 1.0f;
}

// ---------------------------------------------------------------
// prep: u = unfold(x); activations in bf16, MFMA-B-fragment order.
//   Bsb[(f*64 + b)*8 + t]        = spline basis t  (k = f*8+t)
//   Abb[((f>>3)*64 + b)*8 + f&7] = silu(u)         (k = f)
// ---------------------------------------------------------------
__global__ __launch_bounds__(256) void prep_kernel(const float* __restrict__ x,
                                                   __bf16* __restrict__ Abb,
                                                   __bf16* __restrict__ Bsb) {
    int tid = blockIdx.x * 256 + threadIdx.x;   // tid = f*64 + b
    if (tid >= IN_F * BATCH) return;
    int f = tid >> 6, b = tid & 63;
    int ckk = f >> 4, s = f & 15;
    int c = ckk / 9, r = ckk % 9;
    int ki = r / 3, kj = r % 3;
    int oh = s >> 2, ow = s & 3;
    int h = ki + oh * SST - PPD;
    int w = kj + ow * SST - PPD;
    float u = 0.0f;
    if (h >= 0 && h < HIN && w >= 0 && w < WINW)
        u = x[((b * CIN + c) * HIN + h) * WINW + w];

    Abb[((f >> 3) * 64 + b) * 8 + (f & 7)] = (__bf16)(u / (1.0f + __expf(-u)));

    // degree-3 B-spline bases (Cox-de Boor, matches reference)
    float bs[11];
#pragma unroll
    for (int t = 0; t < 11; ++t)
        bs[t] = (u >= gridv(t) && u < gridv(t + 1)) ? 1.0f : 0.0f;
#pragma unroll
    for (int k = 1; k <= 3; ++k) {
#pragma unroll
        for (int i = 0; i < 11; ++i) {
            if (i < 11 - k) {
                float g_i  = gridv(i);
                float g_ik = gridv(i + k);
                float g_i1 = gridv(i + 1);
                float g_k1 = gridv(i + k + 1);
                bs[i] = (u - g_i) / (g_ik - g_i) * bs[i]
                      + (g_k1 - u) / (g_k1 - g_i1) * bs[i + 1];
            }
        }
    }
    bf16x8 v;
#pragma unroll
    for (int t = 0; t < 8; ++t) v[t] = (__bf16)bs[t];
    *(bf16x8*)&Bsb[(size_t)(f * 64 + b) * 8] = v;
}

// ---------------------------------------------------------------
// MFMA GEMM, weights streamed fp32 -> cvt bf16 in-register.
// Block: 4 waves, SAME 16-o tile, 4 consecutive K-chunks (LDS-reduced).
// Wave: 16 o x 64 b (4 b-tiles), K-chunk of FW f's.
// A-frag (16x16x32): lane holds W'[o0 + (l&15)][k0 + (l>>4)*8 + j] -> for
// spline k=f*8+t this is exactly Ws[o][f][0..7] (contiguous!), Sc folded.
// ---------------------------------------------------------------
__global__ __launch_bounds__(256, 4) void gemm_kernel(
    const float* __restrict__ Wb,    // (OUT_F, IN_F)
    const float* __restrict__ Ws,    // (OUT_F, IN_F, 8)
    const float* __restrict__ Sc,    // (OUT_F, IN_F)
    const __bf16* __restrict__ Abb,  // base B-frags
    const __bf16* __restrict__ Bsb,  // spline B-frags
    float* __restrict__ partial)     // (OS, OUT_F, 64)
{
    __shared__ f32x4 red[4 * 256];   // 16 KB

    const int tid  = threadIdx.x;
    const int lane = tid & 63;
    const int wv   = tid >> 6;
    const int ot = blockIdx.x / OS;
    const int os = blockIdx.x % OS;
    const int o0 = ot * 16;
    const int f0 = (os * 4 + wv) * FW;
    const int lr = lane & 15;        // A-row (o), B-col (b), D-col (b)
    const int lg = lane >> 4;        // k-group
    const int o  = o0 + lr;

    f32x4 acc0 = {0.f,0.f,0.f,0.f}, acc1 = {0.f,0.f,0.f,0.f};
    f32x4 acc2 = {0.f,0.f,0.f,0.f}, acc3 = {0.f,0.f,0.f,0.f};

    const bf16x8* Bv = (const bf16x8*)Bsb;
    const bf16x8* Av = (const bf16x8*)Abb;

    // ---- spline GEMM: K-step 32 = 4 f's ----
    const float* wsrow = Ws + (size_t)o * IN_F * 8;
    const float* scrow = Sc + (size_t)o * IN_F;
#pragma unroll 2
    for (int s = 0; s < FW / 4; ++s) {
        int f = f0 + s * 4 + lg;
        float4 w0 = *(const float4*)&wsrow[(size_t)f * 8];
        float4 w1 = *(const float4*)&wsrow[(size_t)f * 8 + 4];
        float sc  = scrow[f];
        bf16x8 af;
        af[0] = (__bf16)(w0.x * sc); af[1] = (__bf16)(w0.y * sc);
        af[2] = (__bf16)(w0.z * sc); af[3] = (__bf16)(w0.w * sc);
        af[4] = (__bf16)(w1.x * sc); af[5] = (__bf16)(w1.y * sc);
        af[6] = (__bf16)(w1.z * sc); af[7] = (__bf16)(w1.w * sc);
        const bf16x8* bb = Bv + (size_t)f * 64 + lr;   // chunk = f*64 + bt*16 + lr
        acc0 = __builtin_amdgcn_mfma_f32_16x16x32_bf16(af, bb[0],  acc0, 0, 0, 0);
        acc1 = __builtin_amdgcn_mfma_f32_16x16x32_bf16(af, bb[16], acc1, 0, 0, 0);
        acc2 = __builtin_amdgcn_mfma_f32_16x16x32_bf16(af, bb[32], acc2, 0, 0, 0);
        acc3 = __builtin_amdgcn_mfma_f32_16x16x32_bf16(af, bb[48], acc3, 0, 0, 0);
    }

    // ---- base GEMM: K-step 32 = 32 f's ----
    const float* wbrow = Wb + (size_t)o * IN_F;
#pragma unroll
    for (int s = 0; s < FW / 32; ++s) {
        int fb = f0 + s * 32 + lg * 8;              // 8 consecutive f for this lane
        float4 w0 = *(const float4*)&wbrow[fb];
        float4 w1 = *(const float4*)&wbrow[fb + 4];
        bf16x8 af;
        af[0] = (__bf16)w0.x; af[1] = (__bf16)w0.y;
        af[2] = (__bf16)w0.z; af[3] = (__bf16)w0.w;
        af[4] = (__bf16)w1.x; af[5] = (__bf16)w1.y;
        af[6] = (__bf16)w1.z; af[7] = (__bf16)w1.w;
        const bf16x8* bb = Av + (size_t)(fb >> 3) * 64 + lr;
        acc0 = __builtin_amdgcn_mfma_f32_16x16x32_bf16(af, bb[0],  acc0, 0, 0, 0);
        acc1 = __builtin_amdgcn_mfma_f32_16x16x32_bf16(af, bb[16], acc1, 0, 0, 0);
        acc2 = __builtin_amdgcn_mfma_f32_16x16x32_bf16(af, bb[32], acc2, 0, 0, 0);
        acc3 = __builtin_amdgcn_mfma_f32_16x16x32_bf16(af, bb[48], acc3, 0, 0, 0);
    }

    // ---- block reduce over the 4 waves' K-chunks ----
    // D layout: lane holds D[(lg)*4 + r][lr] (row=o-in-tile, col=b-in-tile)
    float* red_f = (float*)red;
#pragma unroll
    for (int r = 0; r < 4; ++r) {
        int oi = lg * 4 + r;
        red_f[wv * 1024 + oi * 64 +  0 + lr] = acc0[r];
        red_f[wv * 1024 + oi * 64 + 16 + lr] = acc1[r];
        red_f[wv * 1024 + oi * 64 + 32 + lr] = acc2[r];
        red_f[wv * 1024 + oi * 64 + 48 + lr] = acc3[r];
    }
    __syncthreads();
    f32x4 s4 = red[tid] + red[256 + tid] + red[512 + tid] + red[768 + tid];
    *(f32x4*)&partial[(size_t)os * (OUT_F * 64) + ot * 1024 + tid * 4] = s4;
}

// ---------------------------------------------------------------
// fold + OS-reduce, inverted mapping: one thread per OUTPUT element,
// gathers its <=9 contributing GEMM rows. No atomics, no memset.
// ---------------------------------------------------------------
__global__ __launch_bounds__(256) void fold_kernel(const float* __restrict__ partial,
                                                   float* __restrict__ out) {
    int gid = blockIdx.x * 256 + threadIdx.x;     // 131072 = 64*8*16*16
    int b = gid & 63, p = gid >> 6;
    int w = p & 15, h = (p >> 4) & 15, c = p >> 8;
    float sum = 0.0f;
#pragma unroll
    for (int ki = 0; ki < 3; ++ki) {
        int th = h + 1 - ki;
        if (th < 0 || (th & 1) || (th >> 1) >= 8) continue;
        int oh = th >> 1;
#pragma unroll
        for (int kj = 0; kj < 3; ++kj) {
            int tw = w + 1 - kj;
            if (tw < 0 || (tw & 1) || (tw >> 1) >= 8) continue;
            int ow = tw >> 1;
            int o = ((c * 3 + ki) * 3 + kj) * 64 + oh * 8 + ow;
            const float* pp = partial + (size_t)o * 64 + b;
#pragma unroll
            for (int os = 0; os < OS; ++os)
                sum += pp[(size_t)os * (OUT_F * 64)];
        }
    }
    out[((b * COUTC + c) * HOUTC + h) * WOUTC + w] = sum;
}

extern "C" void kernel_launch(void* const* d_in, const int* in_sizes, int n_in,
                              void* d_out, int out_size, void* d_ws, size_t ws_size,
                              hipStream_t stream) {
    const float* x  = (const float*)d_in[0];
    const float* Wb = (const float*)d_in[1];
    const float* Ws = (const float*)d_in[2];
    const float* Sc = (const float*)d_in[3];
    // d_in[4] = grid, recomputed analytically (uniform knots)

    float* out = (float*)d_out;

    __bf16* Abb    = (__bf16*)d_ws;                          // IN_F*64 bf16
    __bf16* Bsb    = Abb + (size_t)IN_F * BATCH;             // IN_F*64*8 bf16
    float*  partial = (float*)(Bsb + (size_t)IN_F * BATCH * 8); // OS*OUT_F*64 f32 (7.1 MB)

    prep_kernel<<<(IN_F * BATCH + 255) / 256, 256, 0, stream>>>(x, Abb, Bsb);

    gemm_kernel<<<(OUT_F / 16) * OS, 256, 0, stream>>>(Wb, Ws, Sc, Abb, Bsb, partial);

    fold_kernel<<<(BATCH * COUTC * HOUTC * WOUTC) / 256, 256, 0, stream>>>(partial, out);
}